// Round 1
// baseline (643.726 us; speedup 1.0000x reference)
//
#include <hip/hip_runtime.h>
#include <cstdint>
#include <cstddef>

#define B_ROWS 65536
#define OUT_N  2048
#define IN_K   64
#define LOG2E  1.4426950408889634f

typedef __attribute__((ext_vector_type(8))) short bf16x8;
typedef __attribute__((ext_vector_type(4))) float f32x4;
typedef __attribute__((ext_vector_type(4))) short s16x4;

__device__ __forceinline__ unsigned short f2bf_rtn(float v) {
  unsigned u = __float_as_uint(v);
  u += 0x7fffu + ((u >> 16) & 1u);
  return (unsigned short)(u >> 16);
}
__device__ __forceinline__ float bf2f(unsigned short s) {
  return __uint_as_float(((unsigned)s) << 16);
}

// Precompute: centers -> bf16 hi/lo split, c2 = sum(c^2), iv = exp(-2*ls)*log2e
__global__ __launch_bounds__(64) void rbf_pre(
    const float* __restrict__ centers, const float* __restrict__ log_sigmas,
    unsigned short* __restrict__ ch, unsigned short* __restrict__ cl,
    float* __restrict__ c2, float* __restrict__ iv) {
  const int o = blockIdx.x;
  const int lane = threadIdx.x;
  float v = centers[o * IN_K + lane];
  unsigned short h = f2bf_rtn(v);
  float hf = bf2f(h);
  unsigned short l = f2bf_rtn(v - hf);
  ch[o * IN_K + lane] = h;
  cl[o * IN_K + lane] = l;
  float s = v * v;
  #pragma unroll
  for (int off = 32; off > 0; off >>= 1) s += __shfl_down(s, off, 64);
  if (lane == 0) {
    c2[o] = s;
    float ls = log_sigmas[o];
    iv[o] = __builtin_amdgcn_exp2f(-2.0f * ls * LOG2E) * LOG2E;
  }
}

// Main: each block owns 64 rows of x, sweeps all 2048 centers.
// MFMA roles: A = centers tile (m = o), B = x tile (n = b).
// C/D layout (gfx950 16x16x32): col = lane&15 -> b ; row = quad*4+reg -> o
// => each lane stores 4 consecutive o's as one dwordx4.
__global__ __launch_bounds__(256) void rbf_main(
    const float* __restrict__ x,
    const unsigned short* __restrict__ ch, const unsigned short* __restrict__ cl,
    const float* __restrict__ c2, const float* __restrict__ iv,
    float* __restrict__ out) {
  // 72-short row pitch (+16B) breaks the 128B power-of-2 stride -> only 2-way
  // bank aliasing on ds_read_b128, which is free on CDNA4.
  __shared__ unsigned short xh[64 * 72];
  __shared__ unsigned short xl[64 * 72];
  __shared__ float x2s[64];

  const int t = threadIdx.x;
  const int b0 = blockIdx.x * 64;

  if (t < 64) x2s[t] = 0.0f;
  __syncthreads();

  // Stage x tile: 64 rows x 64 cols fp32 = 1024 float4, 4 per thread (coalesced)
  const f32x4* xv = (const f32x4*)(x + (size_t)b0 * IN_K);
  #pragma unroll
  for (int i = 0; i < 4; ++i) {
    int f4 = i * 256 + t;            // 0..1023
    f32x4 v = xv[f4];
    int row = f4 >> 4;               // 16 float4 per row
    int col = (f4 & 15) * 4;
    s16x4 h, l;
    #pragma unroll
    for (int j = 0; j < 4; ++j) {
      unsigned short hh = f2bf_rtn(v[j]);
      h[j] = (short)hh;
      l[j] = (short)f2bf_rtn(v[j] - bf2f(hh));
    }
    *(s16x4*)(xh + row * 72 + col) = h;
    *(s16x4*)(xl + row * 72 + col) = l;
    atomicAdd(&x2s[row], v[0] * v[0] + v[1] * v[1] + v[2] * v[2] + v[3] * v[3]);
  }
  __syncthreads();

  const int lane = t & 63;
  const int w    = t >> 6;        // wave id 0..3
  const int n    = lane & 15;     // free-index for both A and B operands
  const int quad = lane >> 4;
  const int kq   = quad * 8;      // k-offset within 32-chunk

  for (int oc = 0; oc < OUT_N; oc += 256) {
    const int obase = oc + w * 64;          // each wave owns 64 consecutive o
    #pragma unroll
    for (int mt = 0; mt < 4; ++mt) {
      const int o0 = obase + mt * 16;
      const int arow = o0 + n;
      // A-frags: centers rows (hi and lo), K halves 0..31 / 32..63
      bf16x8 ah0 = *(const bf16x8*)(ch + arow * IN_K + kq);
      bf16x8 ah1 = *(const bf16x8*)(ch + arow * IN_K + kq + 32);
      bf16x8 al0 = *(const bf16x8*)(cl + arow * IN_K + kq);
      bf16x8 al1 = *(const bf16x8*)(cl + arow * IN_K + kq + 32);
      f32x4 c2v = *(const f32x4*)(c2 + o0 + quad * 4);
      f32x4 ivv = *(const f32x4*)(iv + o0 + quad * 4);
      #pragma unroll
      for (int nt = 0; nt < 4; ++nt) {
        const int brow = nt * 16 + n;
        const unsigned short* bp  = xh + brow * 72 + kq;
        const unsigned short* bpl = xl + brow * 72 + kq;
        bf16x8 bh0 = *(const bf16x8*)(bp);
        bf16x8 bh1 = *(const bf16x8*)(bp + 32);
        bf16x8 bl0 = *(const bf16x8*)(bpl);
        bf16x8 bl1 = *(const bf16x8*)(bpl + 32);
        f32x4 acc = {0.0f, 0.0f, 0.0f, 0.0f};
        // 3-pass split-precision dot: hh + h*l + l*h (l*l ~2^-16 rel, dropped)
        acc = __builtin_amdgcn_mfma_f32_16x16x32_bf16(ah0, bh0, acc, 0, 0, 0);
        acc = __builtin_amdgcn_mfma_f32_16x16x32_bf16(ah1, bh1, acc, 0, 0, 0);
        acc = __builtin_amdgcn_mfma_f32_16x16x32_bf16(ah0, bl0, acc, 0, 0, 0);
        acc = __builtin_amdgcn_mfma_f32_16x16x32_bf16(ah1, bl1, acc, 0, 0, 0);
        acc = __builtin_amdgcn_mfma_f32_16x16x32_bf16(al0, bh0, acc, 0, 0, 0);
        acc = __builtin_amdgcn_mfma_f32_16x16x32_bf16(al1, bh1, acc, 0, 0, 0);
        const float x2v = x2s[brow];
        f32x4 r;
        #pragma unroll
        for (int j = 0; j < 4; ++j) {
          float sq = x2v - 2.0f * acc[j] + c2v[j];
          sq = fmaxf(sq, 0.0f);                      // match ref clamp
          r[j] = __builtin_amdgcn_exp2f(-sq * ivv[j]);
        }
        *(f32x4*)(out + (size_t)(b0 + brow) * OUT_N + o0 + quad * 4) = r;
      }
    }
  }
}

extern "C" void kernel_launch(void* const* d_in, const int* in_sizes, int n_in,
                              void* d_out, int out_size, void* d_ws, size_t ws_size,
                              hipStream_t stream) {
  (void)in_sizes; (void)n_in; (void)out_size; (void)ws_size;
  const float* x       = (const float*)d_in[0];
  const float* centers = (const float*)d_in[1];
  const float* ls      = (const float*)d_in[2];
  float* out = (float*)d_out;

  // ws layout: c_hi (256KB) | c_lo (256KB) | c2 (8KB) | inv2 (8KB)  = 528KB
  char* ws = (char*)d_ws;
  unsigned short* ch = (unsigned short*)(ws);
  unsigned short* cl = (unsigned short*)(ws + 262144);
  float* c2 = (float*)(ws + 524288);
  float* iv = (float*)(ws + 532480);

  rbf_pre<<<OUT_N, 64, 0, stream>>>(centers, ls, ch, cl, c2, iv);
  rbf_main<<<B_ROWS / 64, 256, 0, stream>>>(x, ch, cl, c2, iv, out);
}